// Round 14
// baseline (2286.130 us; speedup 1.0000x reference)
//
#include <hip/hip_runtime.h>
#include <cmath>

#define TOTAL_RAYS (131072 * 16)
#define HDIM 64
#define NSHARD 32
#define SHARD_SZ (TOTAL_RAYS / NSHARD)   // 65536

typedef float v2f __attribute__((ext_vector_type(2)));
typedef float v4f __attribute__((ext_vector_type(4)));

// 32 queue counters, each on its own 64B line to kill same-line atomic serialization
__device__ unsigned int g_counters[NSHARD * 16];

__global__ void vis_init_counter() { g_counters[threadIdx.x * 16] = 0u; }

// softplus(x) = max(x,0) + log1p(exp(-|x|)).
// Fast form: v_exp_f32 / v_log_f32 (~2-4 ulp absolute). Verified absmax 0 since round 4.
__device__ __forceinline__ float softplus_f(float x) {
    return fmaxf(x, 0.0f) + __logf(1.0f + __expf(-fabsf(x)));
}

// R11: weights via wave-uniform s_load (scalar-cache broadcast)  -> 1771us.
// R13: 32-way sharded ray queue (atomic serialization)           -> 1400us, VALUBusy 75%.
// R14: the per-CU scalar port saturates (R12: 2x waves = 0 gain). Split each
// W2 row: q=0..7 stays SMEM (s_load/SGPR broadcast), q=8..15 goes through
// uniform-address VMEM (all lanes same addr -> one L1 transaction, broadcast;
// W2=16KB is L1-resident). VMEM issue is per-SIMD -> no scalar-port contention.
extern "C" __global__ void __launch_bounds__(256, 2)   // 128-VGPR cap (R4 lesson: never 64 with acc[32])
vis_trace_kernel(const float* __restrict__ points,
                 const float* __restrict__ cams,
                 const float* __restrict__ W1,
                 const float* __restrict__ b1,
                 const float* __restrict__ W2,
                 const float* __restrict__ b2,
                 const float* __restrict__ W3,
                 const float* __restrict__ b3,
                 int* __restrict__ out)
{
    const v4f* __restrict__ W2v = reinterpret_cast<const v4f*>(W2);  // row k = W2v[k*16 .. k*16+15]
    const float sB3 = b3[0];                                          // uniform -> SGPR, hoisted

    // Opaque zero in a VGPR: forces the compiler to treat W2dyn as divergent
    // -> global_load (VMEM/L1 broadcast path) instead of scalarizing to s_load.
    int lzero;
    asm volatile("v_mov_b32 %0, 0" : "=v"(lzero));
    const v4f* __restrict__ W2dyn = W2v + lzero;

    const int lane = threadIdx.x & 63;
    int cursh = (int)((blockIdx.x * 4u + (threadIdx.x >> 6)) & (NSHARD - 1));
    int drained_cnt = 0;

    bool live = false, maskv = false, mint = false, drained = false;
    float ox = 0.f, oy = 0.f, oz = 0.f, dx = 0.f, dy = 0.f, dz = 0.f;
    float farv = 0.f, dist = 0.f, cur = 0.f, t = 1e-3f;
    int it = 0;
    unsigned int ridx = 0u;

    for (;;) {
        // ---- refill dead lanes from this wave's current queue shard ----
        unsigned long long needm = __ballot(!live);
        if (needm != 0ull && !drained) {
            int cnt = __popcll(needm);
            unsigned int base = 0u;
            if (lane == 0) base = atomicAdd(&g_counters[cursh * 16], (unsigned int)cnt);
            base = (unsigned int)__shfl((int)base, 0);
            if (base >= (unsigned int)SHARD_SZ) {
                cursh = (cursh + 1) & (NSHARD - 1);      // shard empty -> rotate
                if (++drained_cnt >= NSHARD) drained = true;  // saw all shards empty
            } else {
                drained_cnt = 0;
                if (!live) {
                    unsigned int off = base + (unsigned int)__popcll(needm & ((1ull << lane) - 1ull));
                    if (off < (unsigned int)SHARD_SZ) {
                        unsigned int idx = (unsigned int)cursh * SHARD_SZ + off;
                        ridx = idx;
                        const int n = (int)(idx >> 4), c = (int)(idx & 15u);
                        ox = points[3 * n]; oy = points[3 * n + 1]; oz = points[3 * n + 2];
                        const float cx = cams[3 * c], cy = cams[3 * c + 1], cz = cams[3 * c + 2];
                        {
                            #pragma clang fp contract(off)
                            float rx = cx - ox, ry = cy - oy, rz = cz - oz;
                            float nrm = sqrtf(rx * rx + ry * ry + rz * rz);
                            dx = rx / nrm; dy = ry / nrm; dz = rz / nrm;
                            float bq = dx * ox + dy * oy + dz * oz;
                            float oo = ox * ox + oy * oy + oz * oz;
                            float disc = bq * bq - (oo - 1.0f);
                            mint = disc > 0.0f;
                            farv = -bq + sqrtf(fmaxf(disc, 0.0f));
                        }
                        live = true; maskv = true; it = 0;
                        dist = 0.f; cur = 0.f; t = 1e-3f;
                    }
                }
            }
        }
        if (__ballot(live) == 0ull) {
            if (drained) break;
            continue;                                    // shards left -> retry refill
        }

        // ---- one MLP eval at position t (all lanes; !live lanes compute garbage) ----
        float px, py, pz;
        {
            #pragma clang fp contract(off)
            px = ox + t * dx; py = oy + t * dy; pz = oz + t * dz;
        }

        v2f acc[32];
        #pragma unroll
        for (int q = 0; q < 32; ++q) { v2f z = {0.f, 0.f}; acc[q] = z; }

        #pragma unroll 2
        for (int k = 0; k < HDIM; ++k) {
            // W1 columns + b1: uniform scalar loads (adjacent k merge into s_load_dwordx2)
            float a = fmaf(pz, W1[2 * HDIM + k],
                      fmaf(py, W1[HDIM + k],
                           px * W1[k])) + b1[k];
            float hk = softplus_f(a);
            v2f hk2 = {hk, hk};

            // q = 0..7: SMEM half (s_load, SGPR broadcast)
            const v4f* rowS = &W2v[k * 16];
            #pragma unroll
            for (int q = 0; q < 8; ++q) {
                v4f w = rowS[q];
                v2f w0 = __builtin_shufflevector(w, w, 0, 1);
                v2f w1 = __builtin_shufflevector(w, w, 2, 3);
                acc[2 * q]     = __builtin_elementwise_fma(hk2, w0, acc[2 * q]);     // v_pk_fma_f32
                acc[2 * q + 1] = __builtin_elementwise_fma(hk2, w1, acc[2 * q + 1]);
            }
            // q = 8..15: VMEM half (uniform addr -> one 16B L1 transaction, broadcast)
            const v4f* rowV = &W2dyn[k * 16];
            #pragma unroll
            for (int q = 8; q < 16; ++q) {
                v4f w = rowV[q];                              // global_load_dwordx4, L1-resident
                v2f w0 = __builtin_shufflevector(w, w, 0, 1);
                v2f w1 = __builtin_shufflevector(w, w, 2, 3);
                acc[2 * q]     = __builtin_elementwise_fma(hk2, w0, acc[2 * q]);
                acc[2 * q + 1] = __builtin_elementwise_fma(hk2, w1, acc[2 * q + 1]);
            }
        }

        float s3 = 0.f;
        #pragma unroll
        for (int q = 0; q < 32; ++q) {
            float h2 = softplus_f(acc[q].x + b2[2 * q]);
            s3 = fmaf(h2, W3[2 * q], s3);
            float h3 = softplus_f(acc[q].y + b2[2 * q + 1]);
            s3 = fmaf(h3, W3[2 * q + 1], s3);
        }
        const float s = s3 + sB3;

        // ---- state update (reference semantics, incl. it==0 init step) ----
        if (live) {
            if (it == 0) {
                cur = s; maskv = (cur >= 0.0f); dist = 1e-3f + cur;
            } else {
                cur = maskv ? s : cur;
                maskv = maskv && (cur >= 5e-7f);
                dist = maskv ? (dist + cur) : dist;
                maskv = maskv && (dist <= farv);
            }
            ++it; t = dist;
            if (!maskv || it >= 32) {       // frozen or all 32 evals done
                out[ridx] = ((dist > farv) && mint) ? 1 : 0;
                live = false;
            }
        }
    }
}

extern "C" void kernel_launch(void* const* d_in, const int* in_sizes, int n_in,
                              void* d_out, int out_size, void* d_ws, size_t ws_size,
                              hipStream_t stream) {
    const float* points = (const float*)d_in[0];
    const float* cams   = (const float*)d_in[1];
    const float* W1     = (const float*)d_in[2];
    const float* b1     = (const float*)d_in[3];
    const float* W2     = (const float*)d_in[4];
    const float* b2     = (const float*)d_in[5];
    const float* W3     = (const float*)d_in[6];
    const float* b3     = (const float*)d_in[7];
    int* out = (int*)d_out;

    hipLaunchKernelGGL(vis_init_counter, dim3(1), dim3(NSHARD), 0, stream);
    hipLaunchKernelGGL(vis_trace_kernel, dim3(2048), dim3(256), 0, stream,
                       points, cams, W1, b1, W2, b2, W3, b3, out);
}

// Round 15
// 1186.981 us; speedup vs baseline: 1.9260x; 1.9260x over previous
//
#include <hip/hip_runtime.h>
#include <cmath>

#define TOTAL_RAYS (131072 * 16)
#define HDIM 64
#define NSHARD 32
#define SHARD_SZ (TOTAL_RAYS / NSHARD)   // 65536

typedef float v2f __attribute__((ext_vector_type(2)));
typedef float v4f __attribute__((ext_vector_type(4)));

// 32 queue counters, each on its own 64B line to kill same-line atomic serialization
__device__ unsigned int g_counters[NSHARD * 16];

__global__ void vis_init_counter() { g_counters[threadIdx.x * 16] = 0u; }

// softplus(x) = max(x,0) + log1p(exp(-|x|)).
// Fast form: v_exp_f32 / v_log_f32 (~2-4 ulp absolute). Verified absmax 0 since round 4.
__device__ __forceinline__ float softplus_f(float x) {
    return fmaxf(x, 0.0f) + __logf(1.0f + __expf(-fabsf(x)));
}

// R11: weights via wave-uniform s_load (scalar-cache broadcast)  -> 1771us.
// R13: 32-way sharded ray queue (atomic serialization fix)       -> 1400us, VALUBusy 75%.
// R14 FAILED: uniform-address VMEM does NOT broadcast-compress (64x16B through
//   TA/TD even at same address) — SMEM/SGPR is the only wave-broadcast path.
// R15: kill mask_intersection==false rays AT GRAB TIME. Their output is 0
//   regardless of the trace (visibility = (dist>far) && mint), so tracing them
//   is pure waste — and far=-b makes them the long-tail marchers. Refill is a
//   spin loop so DOA rays never occupy an eval slot.
extern "C" __global__ void __launch_bounds__(256, 2)   // 128-VGPR cap (R4 lesson: never 64 with acc[32])
vis_trace_kernel(const float* __restrict__ points,
                 const float* __restrict__ cams,
                 const float* __restrict__ W1,
                 const float* __restrict__ b1,
                 const float* __restrict__ W2,
                 const float* __restrict__ b2,
                 const float* __restrict__ W3,
                 const float* __restrict__ b3,
                 int* __restrict__ out)
{
    const v4f* __restrict__ W2v = reinterpret_cast<const v4f*>(W2);  // row k = W2v[k*16 .. k*16+15]
    const float sB3 = b3[0];                                          // uniform -> SGPR, hoisted

    const int lane = threadIdx.x & 63;
    int cursh = (int)((blockIdx.x * 4u + (threadIdx.x >> 6)) & (NSHARD - 1));
    int drained_cnt = 0;

    bool live = false, maskv = false, mint = false, drained = false;
    float ox = 0.f, oy = 0.f, oz = 0.f, dx = 0.f, dy = 0.f, dz = 0.f;
    float farv = 0.f, dist = 0.f, cur = 0.f, t = 1e-3f;
    int it = 0;
    unsigned int ridx = 0u;

    for (;;) {
        // ---- refill: spin until every lane is live (or queues drained) ----
        for (;;) {
            unsigned long long needm = __ballot(!live);
            if (needm == 0ull || drained) break;
            int cnt = __popcll(needm);
            unsigned int base = 0u;
            if (lane == 0) base = atomicAdd(&g_counters[cursh * 16], (unsigned int)cnt);
            base = (unsigned int)__shfl((int)base, 0);
            if (base >= (unsigned int)SHARD_SZ) {
                cursh = (cursh + 1) & (NSHARD - 1);           // shard empty -> rotate
                if (++drained_cnt >= NSHARD) drained = true;  // saw all shards empty
                continue;
            }
            drained_cnt = 0;
            if (!live) {
                unsigned int off = base + (unsigned int)__popcll(needm & ((1ull << lane) - 1ull));
                if (off < (unsigned int)SHARD_SZ) {
                    unsigned int idx = (unsigned int)cursh * SHARD_SZ + off;
                    const int n = (int)(idx >> 4), c = (int)(idx & 15u);
                    const float pox = points[3 * n], poy = points[3 * n + 1], poz = points[3 * n + 2];
                    const float cx = cams[3 * c], cy = cams[3 * c + 1], cz = cams[3 * c + 2];
                    float tdx, tdy, tdz, tfar;
                    bool tmint;
                    {
                        #pragma clang fp contract(off)
                        float rx = cx - pox, ry = cy - poy, rz = cz - poz;
                        float nrm = sqrtf(rx * rx + ry * ry + rz * rz);
                        tdx = rx / nrm; tdy = ry / nrm; tdz = rz / nrm;
                        float bq = tdx * pox + tdy * poy + tdz * poz;
                        float oo = pox * pox + poy * poy + poz * poz;
                        float disc = bq * bq - (oo - 1.0f);
                        tmint = disc > 0.0f;
                        tfar = -bq + sqrtf(fmaxf(disc, 0.0f));
                    }
                    if (!tmint) {
                        out[idx] = 0;            // dead on arrival: visibility is 0 whatever the trace does
                        // stay !live -> re-request on next spin
                    } else {
                        ridx = idx; mint = tmint; farv = tfar;
                        ox = pox; oy = poy; oz = poz;
                        dx = tdx; dy = tdy; dz = tdz;
                        live = true; maskv = true; it = 0;
                        dist = 0.f; cur = 0.f; t = 1e-3f;
                    }
                }
            }
        }
        if (__ballot(live) == 0ull) break;       // drained and nothing left to trace

        // ---- one MLP eval at position t (all lanes; !live lanes compute garbage) ----
        float px, py, pz;
        {
            #pragma clang fp contract(off)
            px = ox + t * dx; py = oy + t * dy; pz = oz + t * dz;
        }

        v2f acc[32];
        #pragma unroll
        for (int q = 0; q < 32; ++q) { v2f z = {0.f, 0.f}; acc[q] = z; }

        #pragma unroll 2
        for (int k = 0; k < HDIM; ++k) {
            // W1 columns + b1: uniform scalar loads (adjacent k merge into s_load_dwordx2)
            float a = fmaf(pz, W1[2 * HDIM + k],
                      fmaf(py, W1[HDIM + k],
                           px * W1[k])) + b1[k];
            float hk = softplus_f(a);
            v2f hk2 = {hk, hk};
            const v4f* row = &W2v[k * 16];
            #pragma unroll
            for (int q = 0; q < 16; ++q) {
                v4f w = row[q];                               // uniform addr -> s_load, SGPR broadcast
                v2f w0 = __builtin_shufflevector(w, w, 0, 1);
                v2f w1 = __builtin_shufflevector(w, w, 2, 3);
                acc[2 * q]     = __builtin_elementwise_fma(hk2, w0, acc[2 * q]);     // v_pk_fma_f32
                acc[2 * q + 1] = __builtin_elementwise_fma(hk2, w1, acc[2 * q + 1]);
            }
        }

        float s3 = 0.f;
        #pragma unroll
        for (int q = 0; q < 32; ++q) {
            float h2 = softplus_f(acc[q].x + b2[2 * q]);
            s3 = fmaf(h2, W3[2 * q], s3);
            float h3 = softplus_f(acc[q].y + b2[2 * q + 1]);
            s3 = fmaf(h3, W3[2 * q + 1], s3);
        }
        const float s = s3 + sB3;

        // ---- state update (reference semantics, incl. it==0 init step) ----
        if (live) {
            if (it == 0) {
                cur = s; maskv = (cur >= 0.0f); dist = 1e-3f + cur;
            } else {
                cur = maskv ? s : cur;
                maskv = maskv && (cur >= 5e-7f);
                dist = maskv ? (dist + cur) : dist;
                maskv = maskv && (dist <= farv);
            }
            ++it; t = dist;
            if (!maskv || it >= 32) {       // frozen or all 32 evals done
                out[ridx] = ((dist > farv) && mint) ? 1 : 0;
                live = false;
            }
        }
    }
}

extern "C" void kernel_launch(void* const* d_in, const int* in_sizes, int n_in,
                              void* d_out, int out_size, void* d_ws, size_t ws_size,
                              hipStream_t stream) {
    const float* points = (const float*)d_in[0];
    const float* cams   = (const float*)d_in[1];
    const float* W1     = (const float*)d_in[2];
    const float* b1     = (const float*)d_in[3];
    const float* W2     = (const float*)d_in[4];
    const float* b2     = (const float*)d_in[5];
    const float* W3     = (const float*)d_in[6];
    const float* b3     = (const float*)d_in[7];
    int* out = (int*)d_out;

    hipLaunchKernelGGL(vis_init_counter, dim3(1), dim3(NSHARD), 0, stream);
    hipLaunchKernelGGL(vis_trace_kernel, dim3(2048), dim3(256), 0, stream,
                       points, cams, W1, b1, W2, b2, W3, b3, out);
}

// Round 16
// 1172.248 us; speedup vs baseline: 1.9502x; 1.0126x over previous
//
#include <hip/hip_runtime.h>
#include <cmath>

#define TOTAL_RAYS (131072 * 16)
#define HDIM 64
#define NSHARD 32
#define SHARD_SZ (TOTAL_RAYS / NSHARD)   // 65536
#define NLDSQ 5                          // W2 chunks q=11..15 via LDS; q=0..10 via SMEM

typedef float v2f __attribute__((ext_vector_type(2)));
typedef float v4f __attribute__((ext_vector_type(4)));

// 32 queue counters, each on its own 64B line to kill same-line atomic serialization
__device__ unsigned int g_counters[NSHARD * 16];

__global__ void vis_init_counter() { g_counters[threadIdx.x * 16] = 0u; }

// softplus(x) = max(x,0) + log1p(exp(-|x|)).
// Fast form: v_exp_f32 / v_log_f32 (~2-4 ulp absolute). Verified absmax 0 since round 4.
__device__ __forceinline__ float softplus_f(float x) {
    return fmaxf(x, 0.0f) + __logf(1.0f + __expf(-fabsf(x)));
}

// R11: weights via wave-uniform s_load (scalar-cache broadcast)  -> 1771us.
// R13: 32-way sharded ray queue (atomic serialization fix)       -> 1400us, VALUBusy 75%.
// R14 FAILED: uniform-address VMEM does NOT broadcast-compress.
// R15: DOA-ray culling at grab time                              -> 1187us, VALUBusy 67%.
// R16: fleet arithmetic across R10/R11/R13/R15 shows the binder is scalar-K$
//   return BW (~8.6 B/cy/CU measured at saturation); VALU-max needs 12.4 B/cy
//   of weights. Split the stream: 11/16 W2 chunks stay SMEM (8.1 B/cy), 5
//   chunks + layer-1 {W1,b1} go to LDS (384 uniform b128/eval x 4cy = 91% of
//   LDS unit at VALU-max; R10 calibrated uniform b128 = 4 LDS-cy, no dedup).
//   Both shared pipes <= ~95% -> VALU becomes the limiter.
extern "C" __global__ void __launch_bounds__(256, 2)   // 128-VGPR cap (R4 lesson)
vis_trace_kernel(const float* __restrict__ points,
                 const float* __restrict__ cams,
                 const float* __restrict__ W1,
                 const float* __restrict__ b1,
                 const float* __restrict__ W2,
                 const float* __restrict__ b2,
                 const float* __restrict__ W3,
                 const float* __restrict__ b3,
                 int* __restrict__ out)
{
    const v4f* __restrict__ W2v = reinterpret_cast<const v4f*>(W2);  // row k = W2v[k*16 .. k*16+15]
    const float sB3 = b3[0];                                          // uniform -> SGPR, hoisted

    __shared__ v4f sL1[HDIM];            // {W1x[k], W1y[k], W1z[k], b1[k]}
    __shared__ v4f sW2L[HDIM * NLDSQ];   // [k*5+qq] = W2v[k*16 + 11 + qq]

    const int tid = threadIdx.x;
    for (int i = tid; i < HDIM + HDIM * NLDSQ; i += 256) {
        if (i < HDIM) {
            v4f l1 = {W1[i], W1[HDIM + i], W1[2 * HDIM + i], b1[i]};
            sL1[i] = l1;
        } else {
            int j = i - HDIM;
            int k = j / NLDSQ;
            int qq = j - NLDSQ * k;
            sW2L[j] = W2v[k * 16 + 11 + qq];
        }
    }
    __syncthreads();

    const int lane = tid & 63;
    int cursh = (int)((blockIdx.x * 4u + (threadIdx.x >> 6)) & (NSHARD - 1));
    int drained_cnt = 0;

    bool live = false, maskv = false, mint = false, drained = false;
    float ox = 0.f, oy = 0.f, oz = 0.f, dx = 0.f, dy = 0.f, dz = 0.f;
    float farv = 0.f, dist = 0.f, cur = 0.f, t = 1e-3f;
    int it = 0;
    unsigned int ridx = 0u;

    for (;;) {
        // ---- refill: spin until every lane is live (or queues drained) ----
        for (;;) {
            unsigned long long needm = __ballot(!live);
            if (needm == 0ull || drained) break;
            int cnt = __popcll(needm);
            unsigned int base = 0u;
            if (lane == 0) base = atomicAdd(&g_counters[cursh * 16], (unsigned int)cnt);
            base = (unsigned int)__shfl((int)base, 0);
            if (base >= (unsigned int)SHARD_SZ) {
                cursh = (cursh + 1) & (NSHARD - 1);           // shard empty -> rotate
                if (++drained_cnt >= NSHARD) drained = true;  // saw all shards empty
                continue;
            }
            drained_cnt = 0;
            if (!live) {
                unsigned int off = base + (unsigned int)__popcll(needm & ((1ull << lane) - 1ull));
                if (off < (unsigned int)SHARD_SZ) {
                    unsigned int idx = (unsigned int)cursh * SHARD_SZ + off;
                    const int n = (int)(idx >> 4), c = (int)(idx & 15u);
                    const float pox = points[3 * n], poy = points[3 * n + 1], poz = points[3 * n + 2];
                    const float cx = cams[3 * c], cy = cams[3 * c + 1], cz = cams[3 * c + 2];
                    float tdx, tdy, tdz, tfar;
                    bool tmint;
                    {
                        #pragma clang fp contract(off)
                        float rx = cx - pox, ry = cy - poy, rz = cz - poz;
                        float nrm = sqrtf(rx * rx + ry * ry + rz * rz);
                        tdx = rx / nrm; tdy = ry / nrm; tdz = rz / nrm;
                        float bq = tdx * pox + tdy * poy + tdz * poz;
                        float oo = pox * pox + poy * poy + poz * poz;
                        float disc = bq * bq - (oo - 1.0f);
                        tmint = disc > 0.0f;
                        tfar = -bq + sqrtf(fmaxf(disc, 0.0f));
                    }
                    if (!tmint) {
                        out[idx] = 0;            // dead on arrival: visibility is 0 whatever the trace does
                        // stay !live -> re-request on next spin
                    } else {
                        ridx = idx; mint = tmint; farv = tfar;
                        ox = pox; oy = poy; oz = poz;
                        dx = tdx; dy = tdy; dz = tdz;
                        live = true; maskv = true; it = 0;
                        dist = 0.f; cur = 0.f; t = 1e-3f;
                    }
                }
            }
        }
        if (__ballot(live) == 0ull) break;       // drained and nothing left to trace

        // ---- one MLP eval at position t (all lanes; !live lanes compute garbage) ----
        float px, py, pz;
        {
            #pragma clang fp contract(off)
            px = ox + t * dx; py = oy + t * dy; pz = oz + t * dz;
        }

        v2f acc[32];
        #pragma unroll
        for (int q = 0; q < 32; ++q) { v2f z = {0.f, 0.f}; acc[q] = z; }

        #pragma unroll 2
        for (int k = 0; k < HDIM; ++k) {
            // layer-1 row from LDS (uniform b128): {W1x,W1y,W1z,b1}
            v4f c1 = sL1[k];
            float a = fmaf(pz, c1.z, fmaf(py, c1.y, px * c1.x)) + c1.w;
            float hk = softplus_f(a);
            v2f hk2 = {hk, hk};

            // q = 0..10: SMEM (s_load, SGPR broadcast)
            const v4f* row = &W2v[k * 16];
            #pragma unroll
            for (int q = 0; q < 11; ++q) {
                v4f w = row[q];
                v2f w0 = __builtin_shufflevector(w, w, 0, 1);
                v2f w1 = __builtin_shufflevector(w, w, 2, 3);
                acc[2 * q]     = __builtin_elementwise_fma(hk2, w0, acc[2 * q]);     // v_pk_fma_f32
                acc[2 * q + 1] = __builtin_elementwise_fma(hk2, w1, acc[2 * q + 1]);
            }
            // q = 11..15: LDS (uniform ds_read_b128)
            #pragma unroll
            for (int qq = 0; qq < NLDSQ; ++qq) {
                const int q = 11 + qq;
                v4f w = sW2L[k * NLDSQ + qq];
                v2f w0 = __builtin_shufflevector(w, w, 0, 1);
                v2f w1 = __builtin_shufflevector(w, w, 2, 3);
                acc[2 * q]     = __builtin_elementwise_fma(hk2, w0, acc[2 * q]);
                acc[2 * q + 1] = __builtin_elementwise_fma(hk2, w1, acc[2 * q + 1]);
            }
        }

        float s3 = 0.f;
        #pragma unroll
        for (int q = 0; q < 32; ++q) {
            float h2 = softplus_f(acc[q].x + b2[2 * q]);
            s3 = fmaf(h2, W3[2 * q], s3);
            float h3 = softplus_f(acc[q].y + b2[2 * q + 1]);
            s3 = fmaf(h3, W3[2 * q + 1], s3);
        }
        const float s = s3 + sB3;

        // ---- state update (reference semantics, incl. it==0 init step) ----
        if (live) {
            if (it == 0) {
                cur = s; maskv = (cur >= 0.0f); dist = 1e-3f + cur;
            } else {
                cur = maskv ? s : cur;
                maskv = maskv && (cur >= 5e-7f);
                dist = maskv ? (dist + cur) : dist;
                maskv = maskv && (dist <= farv);
            }
            ++it; t = dist;
            if (!maskv || it >= 32) {       // frozen or all 32 evals done
                out[ridx] = ((dist > farv) && mint) ? 1 : 0;
                live = false;
            }
        }
    }
}

extern "C" void kernel_launch(void* const* d_in, const int* in_sizes, int n_in,
                              void* d_out, int out_size, void* d_ws, size_t ws_size,
                              hipStream_t stream) {
    const float* points = (const float*)d_in[0];
    const float* cams   = (const float*)d_in[1];
    const float* W1     = (const float*)d_in[2];
    const float* b1     = (const float*)d_in[3];
    const float* W2     = (const float*)d_in[4];
    const float* b2     = (const float*)d_in[5];
    const float* W3     = (const float*)d_in[6];
    const float* b3     = (const float*)d_in[7];
    int* out = (int*)d_out;

    hipLaunchKernelGGL(vis_init_counter, dim3(1), dim3(NSHARD), 0, stream);
    hipLaunchKernelGGL(vis_trace_kernel, dim3(2048), dim3(256), 0, stream,
                       points, cams, W1, b1, W2, b2, W3, b3, out);
}

// Round 17
// 1103.688 us; speedup vs baseline: 2.0714x; 1.0621x over previous
//
#include <hip/hip_runtime.h>
#include <cmath>

#define TOTAL_RAYS (131072 * 16)
#define HDIM 64
#define NSHARD 32
#define SHARD_SZ (TOTAL_RAYS / NSHARD)   // 65536
#define CHUNK 64u                        // rays reserved per wave per atomic

typedef float v2f __attribute__((ext_vector_type(2)));
typedef float v4f __attribute__((ext_vector_type(4)));

// 32 queue counters, each on its own 64B line
__device__ unsigned int g_counters[NSHARD * 16];

__global__ void vis_init_counter() { g_counters[threadIdx.x * 16] = 0u; }

// softplus(x) = max(x,0) + log1p(exp(-|x|)).
// Fast form: v_exp_f32 / v_log_f32 (~2-4 ulp absolute). Verified absmax 0 since round 4.
__device__ __forceinline__ float softplus_f(float x) {
    return fmaxf(x, 0.0f) + __logf(1.0f + __expf(-fabsf(x)));
}

// R11: weights via wave-uniform s_load (scalar-cache broadcast)  -> 1771us.
// R13: 32-way sharded ray queue                                  -> 1400us.
// R14 FAILED: uniform-address VMEM does NOT broadcast-compress.
// R15: DOA-ray culling at grab time                              -> 1187us, VALUBusy 67%.
// R16 FALSIFIED scalar-BW cap: -31% SMEM traffic -> dur unchanged. Corrected
//   model: v_pk_fma_f32 is half-rate (157.3TF = scalar ceiling) -> VALU work
//   ~12000cy/eval = 70% of the 17200cy wall; the other 30% is bubbles.
// R17: attack the bubbles. (a) chunked refill: one atomic reserves CHUNK=64
//   rays per wave; doling + DOA culls are wave-local (atomics ~50x rarer,
//   spin rounds lose the ~500cy L2 round-trip). (b) softplus software
//   pipeline: hk(k+1) computed before row-k FMAs so exp/log latency hides
//   under 88cy of pk-FMA issue. Pure-SMEM weights (R15 layout).
extern "C" __global__ void __launch_bounds__(256, 2)   // 128-VGPR cap (R4 lesson)
vis_trace_kernel(const float* __restrict__ points,
                 const float* __restrict__ cams,
                 const float* __restrict__ W1,
                 const float* __restrict__ b1,
                 const float* __restrict__ W2,
                 const float* __restrict__ b2,
                 const float* __restrict__ W3,
                 const float* __restrict__ b3,
                 int* __restrict__ out)
{
    const v4f* __restrict__ W2v = reinterpret_cast<const v4f*>(W2);  // row k = W2v[k*16 .. k*16+15]
    const float sB3 = b3[0];                                          // uniform -> SGPR, hoisted

    const int lane = threadIdx.x & 63;
    int cursh = (int)((blockIdx.x * 4u + (threadIdx.x >> 6)) & (NSHARD - 1));
    int drained_cnt = 0;

    // per-wave reserved ray range [cbase, cend) — wave-uniform values
    unsigned int cbase = 0u, cend = 0u;

    bool live = false, maskv = false, mint = false, drained = false;
    float ox = 0.f, oy = 0.f, oz = 0.f, dx = 0.f, dy = 0.f, dz = 0.f;
    float farv = 0.f, dist = 0.f, cur = 0.f, t = 1e-3f;
    int it = 0;
    unsigned int ridx = 0u;

    for (;;) {
        // ---- refill dead lanes from the wave's reserved chunk (atomic only on exhaustion) ----
        for (;;) {
            unsigned long long needm = __ballot(!live);
            if (needm == 0ull || drained) break;

            unsigned int avail = cend - cbase;
            if (avail == 0u) {
                unsigned int b = 0u;
                if (lane == 0) b = atomicAdd(&g_counters[cursh * 16], CHUNK);
                b = (unsigned int)__shfl((int)b, 0);
                if (b >= (unsigned int)SHARD_SZ) {
                    cursh = (cursh + 1) & (NSHARD - 1);           // shard empty -> rotate
                    if (++drained_cnt >= NSHARD) drained = true;  // all shards seen empty
                } else {
                    drained_cnt = 0;
                    unsigned int e = b + CHUNK;
                    if (e > (unsigned int)SHARD_SZ) e = (unsigned int)SHARD_SZ;
                    cbase = (unsigned int)cursh * SHARD_SZ + b;
                    cend  = (unsigned int)cursh * SHARD_SZ + e;
                }
                continue;                                         // re-evaluate with new chunk
            }

            int cnt = __popcll(needm);
            unsigned int take = ((unsigned int)cnt < avail) ? (unsigned int)cnt : avail;
            unsigned int rank = (unsigned int)__popcll(needm & ((1ull << lane) - 1ull));
            if (!live && rank < take) {
                unsigned int idx = cbase + rank;
                const int n = (int)(idx >> 4), c = (int)(idx & 15u);
                const float pox = points[3 * n], poy = points[3 * n + 1], poz = points[3 * n + 2];
                const float cx = cams[3 * c], cy = cams[3 * c + 1], cz = cams[3 * c + 2];
                float tdx, tdy, tdz, tfar;
                bool tmint;
                {
                    #pragma clang fp contract(off)
                    float rx = cx - pox, ry = cy - poy, rz = cz - poz;
                    float nrm = sqrtf(rx * rx + ry * ry + rz * rz);
                    tdx = rx / nrm; tdy = ry / nrm; tdz = rz / nrm;
                    float bq = tdx * pox + tdy * poy + tdz * poz;
                    float oo = pox * pox + poy * poy + poz * poz;
                    float disc = bq * bq - (oo - 1.0f);
                    tmint = disc > 0.0f;
                    tfar = -bq + sqrtf(fmaxf(disc, 0.0f));
                }
                if (!tmint) {
                    out[idx] = 0;            // DOA: visibility 0 regardless of trace; stay dead
                } else {
                    ridx = idx; mint = tmint; farv = tfar;
                    ox = pox; oy = poy; oz = poz;
                    dx = tdx; dy = tdy; dz = tdz;
                    live = true; maskv = true; it = 0;
                    dist = 0.f; cur = 0.f; t = 1e-3f;
                }
            }
            cbase += take;                                        // wave-uniform advance
        }
        if (__ballot(live) == 0ull) break;       // drained and nothing left to trace

        // ---- one MLP eval at position t (all lanes; !live lanes compute garbage) ----
        float px, py, pz;
        {
            #pragma clang fp contract(off)
            px = ox + t * dx; py = oy + t * dy; pz = oz + t * dz;
        }

        v2f acc[32];
        #pragma unroll
        for (int q = 0; q < 32; ++q) { v2f z = {0.f, 0.f}; acc[q] = z; }

        // layer-1 softplus pipelined one k ahead: hk(k+1)'s exp/log latency
        // hides under row k's 32 pk-FMAs.
        float hk;
        {
            float a0 = fmaf(pz, W1[2 * HDIM], fmaf(py, W1[HDIM], px * W1[0])) + b1[0];
            hk = softplus_f(a0);
        }

        #pragma unroll 2
        for (int k = 0; k < HDIM; ++k) {
            const int kn = (k + 1) & (HDIM - 1);   // k=63 -> row 0 (discarded), stays in-bounds
            float an = fmaf(pz, W1[2 * HDIM + kn],
                       fmaf(py, W1[HDIM + kn],
                            px * W1[kn])) + b1[kn];
            float hkn = softplus_f(an);

            v2f hk2 = {hk, hk};
            const v4f* row = &W2v[k * 16];
            #pragma unroll
            for (int q = 0; q < 16; ++q) {
                v4f w = row[q];                               // uniform addr -> s_load, SGPR broadcast
                v2f w0 = __builtin_shufflevector(w, w, 0, 1);
                v2f w1 = __builtin_shufflevector(w, w, 2, 3);
                acc[2 * q]     = __builtin_elementwise_fma(hk2, w0, acc[2 * q]);     // v_pk_fma_f32
                acc[2 * q + 1] = __builtin_elementwise_fma(hk2, w1, acc[2 * q + 1]);
            }
            hk = hkn;
        }

        float s3 = 0.f;
        #pragma unroll
        for (int q = 0; q < 32; ++q) {
            float h2 = softplus_f(acc[q].x + b2[2 * q]);
            s3 = fmaf(h2, W3[2 * q], s3);
            float h3 = softplus_f(acc[q].y + b2[2 * q + 1]);
            s3 = fmaf(h3, W3[2 * q + 1], s3);
        }
        const float s = s3 + sB3;

        // ---- state update (reference semantics, incl. it==0 init step) ----
        if (live) {
            if (it == 0) {
                cur = s; maskv = (cur >= 0.0f); dist = 1e-3f + cur;
            } else {
                cur = maskv ? s : cur;
                maskv = maskv && (cur >= 5e-7f);
                dist = maskv ? (dist + cur) : dist;
                maskv = maskv && (dist <= farv);
            }
            ++it; t = dist;
            if (!maskv || it >= 32) {       // frozen or all 32 evals done
                out[ridx] = ((dist > farv) && mint) ? 1 : 0;
                live = false;
            }
        }
    }
}

extern "C" void kernel_launch(void* const* d_in, const int* in_sizes, int n_in,
                              void* d_out, int out_size, void* d_ws, size_t ws_size,
                              hipStream_t stream) {
    const float* points = (const float*)d_in[0];
    const float* cams   = (const float*)d_in[1];
    const float* W1     = (const float*)d_in[2];
    const float* b1     = (const float*)d_in[3];
    const float* W2     = (const float*)d_in[4];
    const float* b2     = (const float*)d_in[5];
    const float* W3     = (const float*)d_in[6];
    const float* b3     = (const float*)d_in[7];
    int* out = (int*)d_out;

    hipLaunchKernelGGL(vis_init_counter, dim3(1), dim3(NSHARD), 0, stream);
    hipLaunchKernelGGL(vis_trace_kernel, dim3(2048), dim3(256), 0, stream,
                       points, cams, W1, b1, W2, b2, W3, b3, out);
}

// Round 18
// 910.171 us; speedup vs baseline: 2.5118x; 1.2126x over previous
//
#include <hip/hip_runtime.h>
#include <cmath>

#define TOTAL_RAYS (131072 * 16)
#define HDIM 64
#define NSHARD 32
#define SHARD_SZ (TOTAL_RAYS / NSHARD)   // 65536
#define CHUNK 64u                        // rays reserved per wave per atomic
#define SOLO_MAX 16                      // <=16 live lanes + drained -> wave-per-ray mode

typedef float v2f __attribute__((ext_vector_type(2)));
typedef float v4f __attribute__((ext_vector_type(4)));

// 32 queue counters, each on its own 64B line
__device__ unsigned int g_counters[NSHARD * 16];

__global__ void vis_init_counter() { g_counters[threadIdx.x * 16] = 0u; }

// softplus(x) = max(x,0) + log1p(exp(-|x|)).
// Fast form: v_exp_f32 / v_log_f32 (~2-4 ulp absolute). Verified absmax 0 since round 4.
__device__ __forceinline__ float softplus_f(float x) {
    return fmaxf(x, 0.0f) + __logf(1.0f + __expf(-fabsf(x)));
}

// R11: wave-uniform s_load weights (SMEM broadcast)       -> 1771us.
// R13: 32-way sharded ray queue                           -> 1400us.
// R14 FAILED: uniform-address VMEM does NOT broadcast-compress.
// R15: DOA-ray culling at grab time                       -> 1187us.
// R16 FALSIFIED scalar-BW cap (LDS split: dur unchanged). VALU work ~12000cy/eval.
// R17: chunked refill + pipelined softplus                -> 1104us, VALUBusy ~63%.
// R18: kill the DRAIN TAIL (~250-300us at near-zero occupancy: a wave with 1-2
//   live stragglers still pays full wave-evals for up to 32 iters). Solo mode:
//   when drained && <=SOLO_MAX live, the whole wave computes ONE ray per eval
//   (lane k -> h1[k], lane j -> acc[j], shfl-broadcast chains). Bit-identical
//   accumulation order (ascending-k per j, ascending-j epilogue) => same output
//   regardless of mode => deterministic.
extern "C" __global__ void __launch_bounds__(256, 2)   // 128+ VGPR headroom (R4 lesson)
vis_trace_kernel(const float* __restrict__ points,
                 const float* __restrict__ cams,
                 const float* __restrict__ W1,
                 const float* __restrict__ b1,
                 const float* __restrict__ W2,
                 const float* __restrict__ b2,
                 const float* __restrict__ W3,
                 const float* __restrict__ b3,
                 int* __restrict__ out)
{
    const v4f* __restrict__ W2v = reinterpret_cast<const v4f*>(W2);  // row k = W2v[k*16 .. k*16+15]
    const float sB3 = b3[0];                                          // uniform -> SGPR, hoisted

    const int lane = threadIdx.x & 63;
    int cursh = (int)((blockIdx.x * 4u + (threadIdx.x >> 6)) & (NSHARD - 1));
    int drained_cnt = 0;

    // per-wave reserved ray range [cbase, cend) — wave-uniform values
    unsigned int cbase = 0u, cend = 0u;

    bool live = false, maskv = false, mint = false, drained = false;
    float ox = 0.f, oy = 0.f, oz = 0.f, dx = 0.f, dy = 0.f, dz = 0.f;
    float farv = 0.f, dist = 0.f, cur = 0.f, t = 1e-3f;
    int it = 0;
    unsigned int ridx = 0u;

    for (;;) {
        // ---- refill dead lanes from the wave's reserved chunk (atomic only on exhaustion) ----
        for (;;) {
            unsigned long long needm = __ballot(!live);
            if (needm == 0ull || drained) break;

            unsigned int avail = cend - cbase;
            if (avail == 0u) {
                unsigned int b = 0u;
                if (lane == 0) b = atomicAdd(&g_counters[cursh * 16], CHUNK);
                b = (unsigned int)__shfl((int)b, 0);
                if (b >= (unsigned int)SHARD_SZ) {
                    cursh = (cursh + 1) & (NSHARD - 1);           // shard empty -> rotate
                    if (++drained_cnt >= NSHARD) drained = true;  // all shards seen empty
                } else {
                    drained_cnt = 0;
                    unsigned int e = b + CHUNK;
                    if (e > (unsigned int)SHARD_SZ) e = (unsigned int)SHARD_SZ;
                    cbase = (unsigned int)cursh * SHARD_SZ + b;
                    cend  = (unsigned int)cursh * SHARD_SZ + e;
                }
                continue;                                         // re-evaluate with new chunk
            }

            int cnt = __popcll(needm);
            unsigned int take = ((unsigned int)cnt < avail) ? (unsigned int)cnt : avail;
            unsigned int rank = (unsigned int)__popcll(needm & ((1ull << lane) - 1ull));
            if (!live && rank < take) {
                unsigned int idx = cbase + rank;
                const int n = (int)(idx >> 4), c = (int)(idx & 15u);
                const float pox = points[3 * n], poy = points[3 * n + 1], poz = points[3 * n + 2];
                const float cx = cams[3 * c], cy = cams[3 * c + 1], cz = cams[3 * c + 2];
                float tdx, tdy, tdz, tfar;
                bool tmint;
                {
                    #pragma clang fp contract(off)
                    float rx = cx - pox, ry = cy - poy, rz = cz - poz;
                    float nrm = sqrtf(rx * rx + ry * ry + rz * rz);
                    tdx = rx / nrm; tdy = ry / nrm; tdz = rz / nrm;
                    float bq = tdx * pox + tdy * poy + tdz * poz;
                    float oo = pox * pox + poy * poy + poz * poz;
                    float disc = bq * bq - (oo - 1.0f);
                    tmint = disc > 0.0f;
                    tfar = -bq + sqrtf(fmaxf(disc, 0.0f));
                }
                if (!tmint) {
                    out[idx] = 0;            // DOA: visibility 0 regardless of trace; stay dead
                } else {
                    ridx = idx; mint = tmint; farv = tfar;
                    ox = pox; oy = poy; oz = poz;
                    dx = tdx; dy = tdy; dz = tdz;
                    live = true; maskv = true; it = 0;
                    dist = 0.f; cur = 0.f; t = 1e-3f;
                }
            }
            cbase += take;                                        // wave-uniform advance
        }

        unsigned long long lvm = __ballot(live);
        if (lvm == 0ull) break;                  // drained and nothing left to trace

        // ---- solo drain: queues empty, few stragglers -> whole wave per ray ----
        if (drained && __popcll(lvm) <= SOLO_MAX) {
            const float w1x = W1[lane], w1y = W1[HDIM + lane], w1z = W1[2 * HDIM + lane];
            const float b1l = b1[lane], b2l = b2[lane];
            for (;;) {
                unsigned long long lm = __ballot(live);
                if (lm == 0ull) break;
                const int owner = (int)__builtin_ctzll(lm);
                float sox = __shfl(ox, owner), soy = __shfl(oy, owner), soz = __shfl(oz, owner);
                float sdx = __shfl(dx, owner), sdy = __shfl(dy, owner), sdz = __shfl(dz, owner);
                float sfar = __shfl(farv, owner), sdist = __shfl(dist, owner), st = __shfl(t, owner);
                int sit = __shfl(it, owner);
                unsigned int srid = (unsigned int)__shfl((int)ridx, owner);

                for (;;) {
                    float px, py, pz;
                    {
                        #pragma clang fp contract(off)
                        px = sox + st * sdx; py = soy + st * sdy; pz = soz + st * sdz;
                    }
                    // layer-1: lane k computes h1[k] (identical scalar expr/order as batch)
                    float a = fmaf(pz, w1z, fmaf(py, w1y, px * w1x)) + b1l;
                    float hk = softplus_f(a);
                    // layer-2: lane j owns acc[j]; ascending-k fma chain (bit-identical)
                    float accj = 0.f;
                    #pragma unroll 8
                    for (int k = 0; k < HDIM; ++k) {
                        float hs = __shfl(hk, k);                 // broadcast h1[k]
                        accj = fmaf(hs, W2[k * HDIM + lane], accj);
                    }
                    // layer-3: per-lane softplus, then serial ascending-j chain (bit-identical)
                    float h2 = softplus_f(accj + b2l);
                    float s3 = 0.f;
                    #pragma unroll 8
                    for (int j = 0; j < HDIM; ++j)
                        s3 = fmaf(__shfl(h2, j), W3[j], s3);      // W3[j] uniform -> SGPR
                    const float s = s3 + sB3;

                    bool smask;
                    if (sit == 0) {
                        smask = (s >= 0.0f);
                        sdist = 1e-3f + s;
                    } else {
                        smask = (s >= 5e-7f);
                        sdist = smask ? (sdist + s) : sdist;
                        smask = smask && (sdist <= sfar);
                    }
                    ++sit; st = sdist;
                    if (!smask || sit >= 32) break;
                }
                if (lane == 0) out[srid] = (sdist > sfar) ? 1 : 0;   // mint true by construction
                if (lane == owner) live = false;
            }
            break;                                // wave fully done
        }

        // ---- one batch MLP eval at position t (all lanes; !live lanes compute garbage) ----
        float px, py, pz;
        {
            #pragma clang fp contract(off)
            px = ox + t * dx; py = oy + t * dy; pz = oz + t * dz;
        }

        v2f acc[32];
        #pragma unroll
        for (int q = 0; q < 32; ++q) { v2f z = {0.f, 0.f}; acc[q] = z; }

        // layer-1 softplus pipelined one k ahead: hk(k+1)'s exp/log latency
        // hides under row k's 32 pk-FMAs.
        float hk;
        {
            float a0 = fmaf(pz, W1[2 * HDIM], fmaf(py, W1[HDIM], px * W1[0])) + b1[0];
            hk = softplus_f(a0);
        }

        #pragma unroll 2
        for (int k = 0; k < HDIM; ++k) {
            const int kn = (k + 1) & (HDIM - 1);   // k=63 -> row 0 (discarded), stays in-bounds
            float an = fmaf(pz, W1[2 * HDIM + kn],
                       fmaf(py, W1[HDIM + kn],
                            px * W1[kn])) + b1[kn];
            float hkn = softplus_f(an);

            v2f hk2 = {hk, hk};
            const v4f* row = &W2v[k * 16];
            #pragma unroll
            for (int q = 0; q < 16; ++q) {
                v4f w = row[q];                               // uniform addr -> s_load, SGPR broadcast
                v2f w0 = __builtin_shufflevector(w, w, 0, 1);
                v2f w1 = __builtin_shufflevector(w, w, 2, 3);
                acc[2 * q]     = __builtin_elementwise_fma(hk2, w0, acc[2 * q]);     // v_pk_fma_f32
                acc[2 * q + 1] = __builtin_elementwise_fma(hk2, w1, acc[2 * q + 1]);
            }
            hk = hkn;
        }

        float s3 = 0.f;
        #pragma unroll
        for (int q = 0; q < 32; ++q) {
            float h2 = softplus_f(acc[q].x + b2[2 * q]);
            s3 = fmaf(h2, W3[2 * q], s3);
            float h3 = softplus_f(acc[q].y + b2[2 * q + 1]);
            s3 = fmaf(h3, W3[2 * q + 1], s3);
        }
        const float s = s3 + sB3;

        // ---- state update (reference semantics, incl. it==0 init step) ----
        if (live) {
            if (it == 0) {
                cur = s; maskv = (cur >= 0.0f); dist = 1e-3f + cur;
            } else {
                cur = maskv ? s : cur;
                maskv = maskv && (cur >= 5e-7f);
                dist = maskv ? (dist + cur) : dist;
                maskv = maskv && (dist <= farv);
            }
            ++it; t = dist;
            if (!maskv || it >= 32) {       // frozen or all 32 evals done
                out[ridx] = ((dist > farv) && mint) ? 1 : 0;
                live = false;
            }
        }
    }
}

extern "C" void kernel_launch(void* const* d_in, const int* in_sizes, int n_in,
                              void* d_out, int out_size, void* d_ws, size_t ws_size,
                              hipStream_t stream) {
    const float* points = (const float*)d_in[0];
    const float* cams   = (const float*)d_in[1];
    const float* W1     = (const float*)d_in[2];
    const float* b1     = (const float*)d_in[3];
    const float* W2     = (const float*)d_in[4];
    const float* b2     = (const float*)d_in[5];
    const float* W3     = (const float*)d_in[6];
    const float* b3     = (const float*)d_in[7];
    int* out = (int*)d_out;

    hipLaunchKernelGGL(vis_init_counter, dim3(1), dim3(NSHARD), 0, stream);
    hipLaunchKernelGGL(vis_trace_kernel, dim3(2048), dim3(256), 0, stream,
                       points, cams, W1, b1, W2, b2, W3, b3, out);
}